// Round 1
// baseline (462.340 us; speedup 1.0000x reference)
//
#include <hip/hip_runtime.h>
#include <stdint.h>

// FactorLayer: B=4096, D=4096, T=16, float32.
// X = znorm(inputs); Y = X@W_static; Z = X@W; sequential deflation collapses
// to 17-dim recurrences on the Gram of [Y|Z|1]; Out = Z - [Y|1]@Wmat.
// Structure (R12): 3 launches. kA: stats partials ([16][8192], 512 KB,
// L2-resident) via intra-block LDS reduce + zero gram + zero rg-counters.
// kBC: pure GEMM R = (in.diag(inv)) @ [Wstat|W] with 16 KB inv-prologue,
// weights s_load'ed RAW via wave-uniform jq base select; THEN the kC work
// (ypart reduce + gram) folded in via last-block-per-rowgroup: threadfence +
// per-rg atomic counter; 32nd arriver reduces its 64 rows (256 KB, overlapped
// across 64 consumer blocks) -> kills kC's dispatch + one ~7us launch gap.
// kE: centered-Gram solve (shifts recovered via S_j = raw-Gram col 32).
// Journal: R3 coop launch no-ops. R7: weight ptr off raw t>>7 kills s_load
// (use readfirstlane). Launch gap ~6-7us (R2->R5 calibration). Fixed harness
// cost (fills+restore+gaps) ~110us; controllable kernel floor ~26us.

#define BB 4096
#define DD 4096
#define EPSF 1e-6f

// ws layout (float indices)
#define O_PART    0u          // [16 rowgroups][8192]: colsum(0..4095), colsq(4096..8191)
#define O_GRAMM   131072u     // 8 copies x 1120 (33x33, upper-tri used)
#define O_CNT     140032u     // 64 uint32 rowgroup arrival counters
#define O_YZ      140288u     // [4096][32] raw R (16B-aligned)
#define O_YPART   271360u     // [32 dgroups][4096][32] (16B-aligned)

__device__ __forceinline__ int gidx(int a, int b) {   // upper-tri gram index
    int lo = a < b ? a : b, hi = a < b ? b : a;
    return lo * 33 + hi;
}

// ============ kA: stats partials (16 rowgroups) + zero gram/counters ========
// 512 blocks = 32 colgroups(128 cols) x 16 rowgroups(256 rows).
__global__ __launch_bounds__(256, 2)
void kA(const float* __restrict__ in, float* __restrict__ ws) {
    __shared__ float rs[8 * 132], rq[8 * 132];        // pad 132: avoid 8-way bank hits
    int b = blockIdx.x, t = threadIdx.x;
    int idx = b * 256 + t;
    if (idx < 9024) ws[O_GRAMM + idx] = 0.f;          // 8 gram copies + 64 counters
    int cg = b & 31, rg = b >> 5;
    int dbase = cg * 128, r0 = rg * 256;
    int chunk = t & 31, rr = t >> 5;
    int c0 = dbase + chunk * 4;
    float s0=0.f,s1=0.f,s2=0.f,s3=0.f,q0=0.f,q1=0.f,q2=0.f,q3=0.f;
    #pragma unroll 4
    for (int i = 0; i < 32; ++i) {
        int r = r0 + i * 8 + rr;
        float4 u = *(const float4*)&in[(size_t)r * DD + c0];
        s0 += u.x; q0 += u.x*u.x;  s1 += u.y; q1 += u.y*u.y;
        s2 += u.z; q2 += u.z*u.z;  s3 += u.w; q3 += u.w*u.w;
    }
    int lb = rr * 132 + chunk * 4;
    rs[lb+0]=s0; rs[lb+1]=s1; rs[lb+2]=s2; rs[lb+3]=s3;
    rq[lb+0]=q0; rq[lb+1]=q1; rq[lb+2]=q2; rq[lb+3]=q3;
    __syncthreads();
    float* part = ws + O_PART + (size_t)rg * 8192;
    if (t < 128) {                                    // finalize sums
        float a = 0.f;
        #pragma unroll
        for (int r2 = 0; r2 < 8; ++r2) a += rs[r2 * 132 + t];
        part[dbase + t] = a;
    } else {                                          // finalize sumsqs
        int ci = t - 128;
        float a = 0.f;
        #pragma unroll
        for (int r2 = 0; r2 < 8; ++r2) a += rq[r2 * 132 + ci];
        part[4096 + dbase + ci] = a;
    }
}

// ====== kBC: inv-prologue + pure GEMM + last-block-per-rg reduce/gram =======
// 2048 blocks = 32 dgroups(128 d) x 64 rowgroups(64 rows). 8 blocks/CU.
// Thread: row = t&63, jq = readfirstlane(t>>6) -> j in [jq*8, jq*8+8).
__global__ __launch_bounds__(256, 8)
void kBC(const float* __restrict__ in, const float* __restrict__ W,
         const float* __restrict__ Wstat, float* __restrict__ ws,
         float* __restrict__ ypart) {
    __shared__ __align__(16) float tile[64 * 34];     // stride 33 staging; stride 34 yz reuse
    __shared__ __align__(16) float inv_s[128];
    __shared__ int is_last;
    int b = blockIdx.x, t = threadIdx.x;
    int dg = b & 31, rg = b >> 5;
    int dbase = dg * 128, rowbase = rg * 64;
    int chunk = t & 7, srow = t >> 3;                 // staging role (srow<32)
    int row = t & 63;
    int jq = __builtin_amdgcn_readfirstlane(t >> 6);  // wave-uniform -> s_load
    const float* inp = in + (size_t)(rowbase + srow) * DD + dbase + chunk * 4;
    float4 pf0 = *(const float4*)(inp);               // prefetch overlaps prologue
    float4 pf1 = *(const float4*)(inp + (size_t)32 * DD);
    {   // prologue: inv for this block's 128 cols from 16 KB L2-hot partials
        if (t < 128) {
            const float* part = ws + O_PART;
            float s = 0.f, q = 0.f;
            #pragma unroll
            for (int g = 0; g < 16; ++g) {
                s += part[(size_t)g * 8192 + dbase + t];
                q += part[(size_t)g * 8192 + 4096 + dbase + t];
            }
            float m = s * (1.0f / BB);
            float var = q * (1.0f / BB) - m * m; if (var < 0.f) var = 0.f;
            inv_s[t] = 1.0f / (sqrtf(var) + EPSF);
        }
        __syncthreads();
    }
    float acc[8];
    #pragma unroll
    for (int i = 0; i < 8; ++i) acc[i] = 0.f;
    // raw weight base: wave-uniform jq -> scalar loads (R7 lesson)
    const float* wbase = (jq < 2) ? (Wstat + jq * 8) : (W + (jq - 2) * 8);
    for (int stage = 0; stage < 4; ++stage) {
        int ds0 = stage * 32;
        float4 iv4 = *(const float4*)&inv_s[ds0 + chunk * 4];
        int b0 = srow * 33 + chunk * 4;               // scale folded into staging
        tile[b0 + 0] = pf0.x * iv4.x; tile[b0 + 1] = pf0.y * iv4.y;
        tile[b0 + 2] = pf0.z * iv4.z; tile[b0 + 3] = pf0.w * iv4.w;
        int b1 = (srow + 32) * 33 + chunk * 4;
        tile[b1 + 0] = pf1.x * iv4.x; tile[b1 + 1] = pf1.y * iv4.y;
        tile[b1 + 2] = pf1.z * iv4.z; tile[b1 + 3] = pf1.w * iv4.w;
        __syncthreads();
        if (stage < 3) {                              // prefetch next stage
            pf0 = *(const float4*)(inp + (stage + 1) * 32);
            pf1 = *(const float4*)(inp + (size_t)32 * DD + (stage + 1) * 32);
        }
        const float* trow = tile + row * 33;
        #pragma unroll 4
        for (int dl = 0; dl < 32; ++dl) {
            float xs = trow[dl];
            const float* wr = wbase + (size_t)(dbase + ds0 + dl) * 16;
            #pragma unroll
            for (int j = 0; j < 8; ++j) acc[j] += xs * wr[j];
        }
        __syncthreads();
    }
    float* dst = ypart + ((size_t)dg * BB + rowbase + row) * 32 + jq * 8;
    *(float4*)(dst + 0) = make_float4(acc[0], acc[1], acc[2], acc[3]);
    *(float4*)(dst + 4) = make_float4(acc[4], acc[5], acc[6], acc[7]);

    // ---- last-block-per-rowgroup: fold kC (reduce + gram) into this launch.
    // Canonical pattern: per-thread device fence, block barrier, t0 counter
    // atomic; 32nd arriver acquires + reduces. No co-residency assumption.
    __threadfence();
    __syncthreads();
    if (t == 0) {
        unsigned int* cnt = (unsigned int*)(ws + O_CNT);
        is_last = (atomicAdd(&cnt[rg], 1u) == 31u);
    }
    __syncthreads();
    if (!is_last) return;
    __threadfence();                                  // acquire side

    // reduce 32 dgroup partials for rows [rowbase, rowbase+64) -> yz + LDS
    float* yz_s = tile;                               // reuse, stride 34
    #pragma unroll
    for (int k = 0; k < 2; ++k) {
        int idx = k * 256 + t;                        // 0..511 = 64 rows x 8 quads
        int r = idx >> 3, q = (idx & 7) * 4;
        size_t off = (size_t)(rowbase + r) * 32 + q;
        float x0=0.f, x1=0.f, x2=0.f, x3=0.f;
        #pragma unroll 8
        for (int dg2 = 0; dg2 < 32; ++dg2) {
            float4 v = *(const float4*)&ypart[(size_t)dg2 * (BB * 32) + off];
            x0 += v.x; x1 += v.y; x2 += v.z; x3 += v.w;
        }
        *(float4*)&ws[O_YZ + off] = make_float4(x0, x1, x2, x3);
        int lbase = r * 34 + q;
        yz_s[lbase + 0] = x0; yz_s[lbase + 1] = x1;
        yz_s[lbase + 2] = x2; yz_s[lbase + 3] = x3;
        if (q == 0) yz_s[r * 34 + 32] = 1.0f;         // ones column
    }
    __syncthreads();
    float* gm = ws + O_GRAMM + (size_t)(rg & 7) * 1120;
    for (int p = t; p < 561; p += 256) {              // upper-tri pairs i<=j<=32
        int i = 0, rem = p;
        while (rem >= 33 - i) { rem -= 33 - i; ++i; }
        int j = i + rem;
        float a2 = 0.f;
        #pragma unroll 8
        for (int r2 = 0; r2 < 64; ++r2)
            a2 += yz_s[r2 * 34 + i] * yz_s[r2 * 34 + j];
        atomicAdd(&gm[i * 33 + j], a2);
    }
}

// ============ kE: centered-Gram 17-dim solve + epilogue =====================
// Basis p=0..15 -> Y[:,p], p=16 -> ones. True Gram from raw: G = Graw - SS^T/B;
// <P,1> = 0. Epilogue on raw R with ones-row of Wmat adjusted by the shifts.
__global__ __launch_bounds__(256, 2)
void kE(const float* __restrict__ ws, float* __restrict__ out) {
    __shared__ __align__(16) float yzs[64 * 36];      // 64 rows of raw [Ry|Rz]
    __shared__ float Sv[33], GA[17 * 17], gz[17 * 16], v[15][17], gad[15][16],
                     gzd[15][16], gu[17], u[17], st[2], wm[17 * 16];
    int b = blockIdx.x, t = threadIdx.x;
    int rowbase = b * 64;                             // 64 blocks x 64 rows
    const float invB = 1.0f / BB;
    const float4* src = (const float4*)(ws + O_YZ) + (size_t)rowbase * 8;
    #pragma unroll
    for (int k = 0; k < 2; ++k) {
        int idx = k * 256 + t;
        float4 f = src[idx];
        int row = idx >> 3, c4 = (idx & 7) * 4;
        yzs[row * 36 + c4 + 0] = f.x; yzs[row * 36 + c4 + 1] = f.y;
        yzs[row * 36 + c4 + 2] = f.z; yzs[row * 36 + c4 + 3] = f.w;
    }
    const float* gm = ws + O_GRAMM;
    if (t < 33) {                                     // S_i = <R_i, 1> (i=32: B)
        float s = 0.f;
        #pragma unroll
        for (int m = 0; m < 8; ++m) s += gm[m * 1120 + gidx(t, 32)];
        Sv[t] = s;
    }
    __syncthreads();
    for (int idx = t; idx < 17 * 17; idx += 256) {    // centered GA
        int p = idx / 17, q = idx % 17;
        float val;
        if (p < 16 && q < 16) {
            float raw = 0.f;
            #pragma unroll
            for (int m = 0; m < 8; ++m) raw += gm[m * 1120 + gidx(p, q)];
            val = raw - Sv[p] * Sv[q] * invB;
        } else if (p == 16 && q == 16) val = (float)BB;
        else val = 0.f;                               // <P,1> = 0 exactly
        GA[idx] = val;
    }
    for (int idx = t; idx < 17 * 16; idx += 256) {    // centered gz
        int p = idx / 16, tt = idx % 16;
        float val = 0.f;
        if (p < 16) {
            float raw = 0.f;
            #pragma unroll
            for (int m = 0; m < 8; ++m) raw += gm[m * 1120 + gidx(p, 16 + tt)];
            val = raw - Sv[p] * Sv[16 + tt] * invB;
        }
        gz[idx] = val;
    }
    if (t < 17) u[t] = (t == 0) ? 1.f : 0.f;
    __syncthreads();
    for (int i = 0; i < 15; ++i) {
        if (t < 17) {                                 // gu = GA @ u
            float s = 0.f;
            for (int q = 0; q < 17; ++q) s += GA[t * 17 + q] * u[q];
            gu[t] = s;
        }
        __syncthreads();
        if (t == 0) {                                 // stats of c_i
            float mean = gu[16] * invB, e2 = 0.f;
            for (int p = 0; p < 17; ++p) e2 += u[p] * gu[p];
            e2 *= invB;
            float var = e2 - mean * mean; if (var < 0.f) var = 0.f;
            st[0] = mean; st[1] = 1.0f / (sqrtf(var) + EPSF);
        }
        __syncthreads();
        if (t < 17) v[i][t] = (u[t] - (t == 16 ? st[0] : 0.f)) * st[1];
        __syncthreads();
        if (t < 16) {                                 // conv_i . Y[:,k]
            float s = 0.f;
            for (int p = 0; p < 17; ++p) s += v[i][p] * GA[p * 17 + t];
            gad[i][t] = s;
        } else if (t < 32) {                          // conv_i . Z[:,tt]
            int tt = t - 16;
            float s = 0.f;
            for (int p = 0; p < 17; ++p) s += v[i][p] * gz[p * 16 + tt];
            gzd[i][tt] = s;
        }
        __syncthreads();
        if (t < 17) {                                 // u_{i+1}
            float a2 = 0.f;
            for (int j = 0; j <= i; ++j) a2 += v[j][t] * gad[j][i + 1];
            u[t] = ((t == i + 1) ? 1.f : 0.f) - a2 * invB;
        }
        __syncthreads();
    }
    for (int idx = t; idx < 17 * 16; idx += 256) {
        int p = idx / 16, tt = idx % 16;
        float s = 0.f;
        for (int j = 0; j < tt; ++j) s += v[j][p] * gzd[j][tt];
        wm[idx] = s * invB;
    }
    __syncthreads();
    if (t < 16) {                                     // fold shifts into ones-row
        float adj = Sv[16 + t] * invB;
        for (int p = 0; p < 16; ++p) adj -= Sv[p] * invB * wm[p * 16 + t];
        wm[16 * 16 + t] += adj;
    }
    __syncthreads();
    int row = t >> 2, c0 = (t & 3) * 4;
    const float* yr = yzs + row * 36;
    float o[4];
    #pragma unroll
    for (int k = 0; k < 4; ++k) o[k] = yr[16 + c0 + k] - wm[16 * 16 + c0 + k];
    #pragma unroll
    for (int p = 0; p < 16; ++p) {
        float yp = yr[p];
        #pragma unroll
        for (int k = 0; k < 4; ++k) o[k] -= yp * wm[p * 16 + c0 + k];
    }
    *(float4*)&out[(size_t)rowbase * 16 + t * 4] = make_float4(o[0], o[1], o[2], o[3]);
}

extern "C" void kernel_launch(void* const* d_in, const int* in_sizes, int n_in,
                              void* d_out, int out_size, void* d_ws, size_t ws_size,
                              hipStream_t stream) {
    const float* in    = (const float*)d_in[0];
    const float* W     = (const float*)d_in[1];
    const float* Wstat = (const float*)d_in[2];
    float* ws  = (float*)d_ws;
    float* out = (float*)d_out;

    kA<<<dim3(512),  dim3(256), 0, stream>>>(in, ws);
    kBC<<<dim3(2048), dim3(256), 0, stream>>>(in, W, Wstat, ws, ws + O_YPART);
    kE<<<dim3(64),   dim3(256), 0, stream>>>(ws, out);
}

// Round 2
// 154.500 us; speedup vs baseline: 2.9925x; 2.9925x over previous
//
#include <hip/hip_runtime.h>
#include <stdint.h>

// FactorLayer: B=4096, D=4096, T=16, float32.
// X = znorm(inputs); Y = X@W_static; Z = X@W; sequential deflation collapses
// to 17-dim recurrences on the Gram of [Y|Z|1]; Out = Z - [Y|1]@Wmat.
// Structure (R13): 4 launches (R12's in-kernel kB->kC fold REVERTED: the
// cross-XCD release fence (__threadfence -> buffer_wbl2/inv per block) cost
// ~360us across 2048 blocks -- plain-store producer/consumer within a launch
// is forbidden on gfx950; kernel boundary is the cheap fence).
// kA: stats partials ([16][8192], 512 KB, L2-resident) via intra-block LDS
// reduce + zero gram. kB: pure GEMM R = (in.diag(inv)) @ [Wstat|W], 16 KB
// inv-prologue per block, weights s_load'ed RAW via wave-uniform jq base
// select. R13 delta: 16 dgroups x 256 cols (was 32x128) -> ypart halves to
// 8.4 MB each way (kC gathers cross-XCD, so this is real HBM traffic).
// kC: reduce + gram. kE: centered-Gram solve (shifts via raw-Gram col 32).
// Journal: R3 coop launch no-ops. R7: weight ptr off raw t>>7 kills s_load
// (use readfirstlane). R12: threadfence fold = +313us FAIL. Launch gap
// ~6-7us. Fixed harness cost (fills+restore+gaps) ~110us; kernel floor ~26us.

#define BB 4096
#define DD 4096
#define EPSF 1e-6f

// ws layout (float indices)
#define O_PART    0u          // [16 rowgroups][8192]: colsum(0..4095), colsq(4096..8191)
#define O_GRAMM   131072u     // 8 copies x 1120 (33x33, upper-tri used)
#define O_YZ      140288u     // [4096][32] raw R (16B-aligned)
#define O_YPART   271360u     // [16 dgroups][4096][32] (16B-aligned)

__device__ __forceinline__ int gidx(int a, int b) {   // upper-tri gram index
    int lo = a < b ? a : b, hi = a < b ? b : a;
    return lo * 33 + hi;
}

// ============ kA: stats partials (16 rowgroups) + zero gram =================
// 512 blocks = 32 colgroups(128 cols) x 16 rowgroups(256 rows).
__global__ __launch_bounds__(256, 2)
void kA(const float* __restrict__ in, float* __restrict__ ws) {
    __shared__ float rs[8 * 132], rq[8 * 132];        // pad 132: avoid 8-way bank hits
    int b = blockIdx.x, t = threadIdx.x;
    int idx = b * 256 + t;
    if (idx < 8960) ws[O_GRAMM + idx] = 0.f;          // 8 gram copies
    int cg = b & 31, rg = b >> 5;
    int dbase = cg * 128, r0 = rg * 256;
    int chunk = t & 31, rr = t >> 5;
    int c0 = dbase + chunk * 4;
    float s0=0.f,s1=0.f,s2=0.f,s3=0.f,q0=0.f,q1=0.f,q2=0.f,q3=0.f;
    #pragma unroll 4
    for (int i = 0; i < 32; ++i) {
        int r = r0 + i * 8 + rr;
        float4 u = *(const float4*)&in[(size_t)r * DD + c0];
        s0 += u.x; q0 += u.x*u.x;  s1 += u.y; q1 += u.y*u.y;
        s2 += u.z; q2 += u.z*u.z;  s3 += u.w; q3 += u.w*u.w;
    }
    int lb = rr * 132 + chunk * 4;
    rs[lb+0]=s0; rs[lb+1]=s1; rs[lb+2]=s2; rs[lb+3]=s3;
    rq[lb+0]=q0; rq[lb+1]=q1; rq[lb+2]=q2; rq[lb+3]=q3;
    __syncthreads();
    float* part = ws + O_PART + (size_t)rg * 8192;
    if (t < 128) {                                    // finalize sums
        float a = 0.f;
        #pragma unroll
        for (int r2 = 0; r2 < 8; ++r2) a += rs[r2 * 132 + t];
        part[dbase + t] = a;
    } else {                                          // finalize sumsqs
        int ci = t - 128;
        float a = 0.f;
        #pragma unroll
        for (int r2 = 0; r2 < 8; ++r2) a += rq[r2 * 132 + ci];
        part[4096 + dbase + ci] = a;
    }
}

// ============ kB: inv-prologue + pure GEMM R = (in.inv) @ Wcat ==============
// 1024 blocks = 16 dgroups(256 d) x 64 rowgroups(64 rows). 4 blocks/CU.
// Thread: row = t&63, jq = readfirstlane(t>>6) -> j in [jq*8, jq*8+8).
__global__ __launch_bounds__(256, 8)
void kB(const float* __restrict__ in, const float* __restrict__ W,
        const float* __restrict__ Wstat, float* __restrict__ ws,
        float* __restrict__ ypart) {
    __shared__ __align__(16) float tile[64 * 33];     // 8.4 KB
    __shared__ __align__(16) float inv_s[256];
    int b = blockIdx.x, t = threadIdx.x;
    int dg = b & 15, rg = b >> 4;
    int dbase = dg * 256, rowbase = rg * 64;
    int chunk = t & 7, srow = t >> 3;                 // staging role (srow<32)
    int row = t & 63;
    int jq = __builtin_amdgcn_readfirstlane(t >> 6);  // wave-uniform -> s_load
    const float* inp = in + (size_t)(rowbase + srow) * DD + dbase + chunk * 4;
    float4 pf0 = *(const float4*)(inp);               // prefetch overlaps prologue
    float4 pf1 = *(const float4*)(inp + (size_t)32 * DD);
    {   // prologue: inv for this block's 256 cols from 32 KB L2-hot partials
        const float* part = ws + O_PART;
        float s = 0.f, q = 0.f;
        #pragma unroll
        for (int g = 0; g < 16; ++g) {
            s += part[(size_t)g * 8192 + dbase + t];
            q += part[(size_t)g * 8192 + 4096 + dbase + t];
        }
        float m = s * (1.0f / BB);
        float var = q * (1.0f / BB) - m * m; if (var < 0.f) var = 0.f;
        inv_s[t] = 1.0f / (sqrtf(var) + EPSF);
        __syncthreads();
    }
    float acc[8];
    #pragma unroll
    for (int i = 0; i < 8; ++i) acc[i] = 0.f;
    // raw weight base: wave-uniform jq -> scalar loads (R7 lesson)
    const float* wbase = (jq < 2) ? (Wstat + jq * 8) : (W + (jq - 2) * 8);
    for (int stage = 0; stage < 8; ++stage) {
        int ds0 = stage * 32;
        float4 iv4 = *(const float4*)&inv_s[ds0 + chunk * 4];
        int b0 = srow * 33 + chunk * 4;               // scale folded into staging
        tile[b0 + 0] = pf0.x * iv4.x; tile[b0 + 1] = pf0.y * iv4.y;
        tile[b0 + 2] = pf0.z * iv4.z; tile[b0 + 3] = pf0.w * iv4.w;
        int b1 = (srow + 32) * 33 + chunk * 4;
        tile[b1 + 0] = pf1.x * iv4.x; tile[b1 + 1] = pf1.y * iv4.y;
        tile[b1 + 2] = pf1.z * iv4.z; tile[b1 + 3] = pf1.w * iv4.w;
        __syncthreads();
        if (stage < 7) {                              // prefetch next stage
            pf0 = *(const float4*)(inp + (stage + 1) * 32);
            pf1 = *(const float4*)(inp + (size_t)32 * DD + (stage + 1) * 32);
        }
        const float* trow = tile + row * 33;
        #pragma unroll 4
        for (int dl = 0; dl < 32; ++dl) {
            float xs = trow[dl];
            const float* wr = wbase + (size_t)(dbase + ds0 + dl) * 16;
            #pragma unroll
            for (int j = 0; j < 8; ++j) acc[j] += xs * wr[j];
        }
        __syncthreads();
    }
    float* dst = ypart + ((size_t)dg * BB + rowbase + row) * 32 + jq * 8;
    *(float4*)(dst + 0) = make_float4(acc[0], acc[1], acc[2], acc[3]);
    *(float4*)(dst + 4) = make_float4(acc[4], acc[5], acc[6], acc[7]);
}

// ============ kC: reduce ypart -> yz (raw R); gram atomics (8-way) ==========
__global__ __launch_bounds__(256, 2)
void kC(float* __restrict__ ws) {
    __shared__ float yz_s[8 * 34];
    int b = blockIdx.x, t = threadIdx.x;
    int rowbase = b * 8;                              // 512 blocks x 8 rows
    int r = t >> 5, c = t & 31;
    const float* yp = ws + O_YPART;
    size_t off = (size_t)(rowbase + r) * 32 + c;
    float s = 0.f;
    #pragma unroll
    for (int dg = 0; dg < 16; ++dg) s += yp[(size_t)dg * (BB * 32) + off];
    ws[O_YZ + off] = s;
    yz_s[r * 34 + c] = s;
    if (c == 0) yz_s[r * 34 + 32] = 1.0f;
    __syncthreads();
    float* gm = ws + O_GRAMM + (size_t)(b & 7) * 1120;
    for (int p = t; p < 561; p += 256) {              // upper-tri pairs i<=j<=32
        int i = 0, rem = p;
        while (rem >= 33 - i) { rem -= 33 - i; ++i; }
        int j = i + rem;
        float a2 = 0.f;
        #pragma unroll
        for (int r2 = 0; r2 < 8; ++r2) a2 += yz_s[r2 * 34 + i] * yz_s[r2 * 34 + j];
        atomicAdd(&gm[i * 33 + j], a2);
    }
}

// ============ kE: centered-Gram 17-dim solve + epilogue =====================
// Basis p=0..15 -> Y[:,p], p=16 -> ones. True Gram from raw: G = Graw - SS^T/B;
// <P,1> = 0. Epilogue on raw R with ones-row of Wmat adjusted by the shifts.
__global__ __launch_bounds__(256, 2)
void kE(const float* __restrict__ ws, float* __restrict__ out) {
    __shared__ __align__(16) float yzs[64 * 36];      // 64 rows of raw [Ry|Rz]
    __shared__ float Sv[33], GA[17 * 17], gz[17 * 16], v[15][17], gad[15][16],
                     gzd[15][16], gu[17], u[17], st[2], wm[17 * 16];
    int b = blockIdx.x, t = threadIdx.x;
    int rowbase = b * 64;                             // 64 blocks x 64 rows
    const float invB = 1.0f / BB;
    const float4* src = (const float4*)(ws + O_YZ) + (size_t)rowbase * 8;
    #pragma unroll
    for (int k = 0; k < 2; ++k) {
        int idx = k * 256 + t;
        float4 f = src[idx];
        int row = idx >> 3, c4 = (idx & 7) * 4;
        yzs[row * 36 + c4 + 0] = f.x; yzs[row * 36 + c4 + 1] = f.y;
        yzs[row * 36 + c4 + 2] = f.z; yzs[row * 36 + c4 + 3] = f.w;
    }
    const float* gm = ws + O_GRAMM;
    if (t < 33) {                                     // S_i = <R_i, 1> (i=32: B)
        float s = 0.f;
        #pragma unroll
        for (int m = 0; m < 8; ++m) s += gm[m * 1120 + gidx(t, 32)];
        Sv[t] = s;
    }
    __syncthreads();
    for (int idx = t; idx < 17 * 17; idx += 256) {    // centered GA
        int p = idx / 17, q = idx % 17;
        float val;
        if (p < 16 && q < 16) {
            float raw = 0.f;
            #pragma unroll
            for (int m = 0; m < 8; ++m) raw += gm[m * 1120 + gidx(p, q)];
            val = raw - Sv[p] * Sv[q] * invB;
        } else if (p == 16 && q == 16) val = (float)BB;
        else val = 0.f;                               // <P,1> = 0 exactly
        GA[idx] = val;
    }
    for (int idx = t; idx < 17 * 16; idx += 256) {    // centered gz
        int p = idx / 16, tt = idx % 16;
        float val = 0.f;
        if (p < 16) {
            float raw = 0.f;
            #pragma unroll
            for (int m = 0; m < 8; ++m) raw += gm[m * 1120 + gidx(p, 16 + tt)];
            val = raw - Sv[p] * Sv[16 + tt] * invB;
        }
        gz[idx] = val;
    }
    if (t < 17) u[t] = (t == 0) ? 1.f : 0.f;
    __syncthreads();
    for (int i = 0; i < 15; ++i) {
        if (t < 17) {                                 // gu = GA @ u
            float s = 0.f;
            for (int q = 0; q < 17; ++q) s += GA[t * 17 + q] * u[q];
            gu[t] = s;
        }
        __syncthreads();
        if (t == 0) {                                 // stats of c_i
            float mean = gu[16] * invB, e2 = 0.f;
            for (int p = 0; p < 17; ++p) e2 += u[p] * gu[p];
            e2 *= invB;
            float var = e2 - mean * mean; if (var < 0.f) var = 0.f;
            st[0] = mean; st[1] = 1.0f / (sqrtf(var) + EPSF);
        }
        __syncthreads();
        if (t < 17) v[i][t] = (u[t] - (t == 16 ? st[0] : 0.f)) * st[1];
        __syncthreads();
        if (t < 16) {                                 // conv_i . Y[:,k]
            float s = 0.f;
            for (int p = 0; p < 17; ++p) s += v[i][p] * GA[p * 17 + t];
            gad[i][t] = s;
        } else if (t < 32) {                          // conv_i . Z[:,tt]
            int tt = t - 16;
            float s = 0.f;
            for (int p = 0; p < 17; ++p) s += v[i][p] * gz[p * 16 + tt];
            gzd[i][tt] = s;
        }
        __syncthreads();
        if (t < 17) {                                 // u_{i+1}
            float a2 = 0.f;
            for (int j = 0; j <= i; ++j) a2 += v[j][t] * gad[j][i + 1];
            u[t] = ((t == i + 1) ? 1.f : 0.f) - a2 * invB;
        }
        __syncthreads();
    }
    for (int idx = t; idx < 17 * 16; idx += 256) {
        int p = idx / 16, tt = idx % 16;
        float s = 0.f;
        for (int j = 0; j < tt; ++j) s += v[j][p] * gzd[j][tt];
        wm[idx] = s * invB;
    }
    __syncthreads();
    if (t < 16) {                                     // fold shifts into ones-row
        float adj = Sv[16 + t] * invB;
        for (int p = 0; p < 16; ++p) adj -= Sv[p] * invB * wm[p * 16 + t];
        wm[16 * 16 + t] += adj;
    }
    __syncthreads();
    int row = t >> 2, c0 = (t & 3) * 4;
    const float* yr = yzs + row * 36;
    float o[4];
    #pragma unroll
    for (int k = 0; k < 4; ++k) o[k] = yr[16 + c0 + k] - wm[16 * 16 + c0 + k];
    #pragma unroll
    for (int p = 0; p < 16; ++p) {
        float yp = yr[p];
        #pragma unroll
        for (int k = 0; k < 4; ++k) o[k] -= yp * wm[p * 16 + c0 + k];
    }
    *(float4*)&out[(size_t)rowbase * 16 + t * 4] = make_float4(o[0], o[1], o[2], o[3]);
}

extern "C" void kernel_launch(void* const* d_in, const int* in_sizes, int n_in,
                              void* d_out, int out_size, void* d_ws, size_t ws_size,
                              hipStream_t stream) {
    const float* in    = (const float*)d_in[0];
    const float* W     = (const float*)d_in[1];
    const float* Wstat = (const float*)d_in[2];
    float* ws  = (float*)d_ws;
    float* out = (float*)d_out;

    kA<<<dim3(512),  dim3(256), 0, stream>>>(in, ws);
    kB<<<dim3(1024), dim3(256), 0, stream>>>(in, W, Wstat, ws, ws + O_YPART);
    kC<<<dim3(512),  dim3(256), 0, stream>>>(ws);
    kE<<<dim3(64),   dim3(256), 0, stream>>>(ws, out);
}

// Round 3
// 146.260 us; speedup vs baseline: 3.1611x; 1.0563x over previous
//
#include <hip/hip_runtime.h>
#include <stdint.h>

// FactorLayer: B=4096, D=4096, T=16, float32.
// X = znorm(inputs); Y = X@W_static; Z = X@W; sequential deflation collapses
// to 17-dim recurrences on the Gram of [Y|Z|1]; Out = Z - [Y|1]@Wmat.
// Structure (R14): 3 launches. kA: stats partials + zero gram/counter.
// kB: EXACT R11 geometry (2048 blocks = 32dg x 64rg, 8 blocks/CU, 32 waves/CU
// -- R13 showed halving blocks to cut ypart bytes loses 5us of latency
// hiding; geometry is load-bearing). kCE: kC+kE fused ATOMICS-ONLY:
// per-block ypart reduce for OWN 64 rows into LDS (yz global array deleted),
// gram via device-scope atomicAdd (coherent, no fence), syncthreads (vmcnt
// drain = release), arrival counter + spin (64 blocks <= 256 CUs, co-resident),
// then solve reads gram via relaxed agent atomic loads (coherent-point reads).
// NO __threadfence anywhere: R12 proved plain-store cross-block handoff costs
// ~360us in buffer_wbl2 flushes; atomics-only handoff needs no cache ops.
// Journal: R3 coop launch no-ops. R7: weight ptr off raw t>>7 kills s_load
// (use readfirstlane). R12 threadfence fold FAIL (+313us). R13 16-dgroup kB
// FAIL (+5us, occupancy). Launch gap ~6-7us. Fixed harness cost ~110us.

#define BB 4096
#define DD 4096
#define EPSF 1e-6f

// ws layout (float indices)
#define O_PART    0u          // [16 rowgroups][8192]: colsum(0..4095), colsq(4096..8191)
#define O_GRAMM   131072u     // 8 copies x 1120 (33x33, upper-tri used)
#define O_CNT     140032u     // 1 uint32 arrival counter (zeroed by kA)
#define O_YPART   271360u     // [32 dgroups][4096][32] (16B-aligned)

__device__ __forceinline__ int gidx(int a, int b) {   // upper-tri gram index
    int lo = a < b ? a : b, hi = a < b ? b : a;
    return lo * 33 + hi;
}

__device__ __forceinline__ float agl(const float* p) { // coherent-point load
    unsigned int u = __hip_atomic_load((const unsigned int*)p,
                                       __ATOMIC_RELAXED, __HIP_MEMORY_SCOPE_AGENT);
    return __uint_as_float(u);
}

// ============ kA: stats partials (16 rowgroups) + zero gram/counter =========
// 512 blocks = 32 colgroups(128 cols) x 16 rowgroups(256 rows).
__global__ __launch_bounds__(256, 2)
void kA(const float* __restrict__ in, float* __restrict__ ws) {
    __shared__ float rs[8 * 132], rq[8 * 132];        // pad 132: avoid 8-way bank hits
    int b = blockIdx.x, t = threadIdx.x;
    int idx = b * 256 + t;
    if (idx < 8961) ws[O_GRAMM + idx] = 0.f;          // 8 gram copies + counter
    int cg = b & 31, rg = b >> 5;
    int dbase = cg * 128, r0 = rg * 256;
    int chunk = t & 31, rr = t >> 5;
    int c0 = dbase + chunk * 4;
    float s0=0.f,s1=0.f,s2=0.f,s3=0.f,q0=0.f,q1=0.f,q2=0.f,q3=0.f;
    #pragma unroll 4
    for (int i = 0; i < 32; ++i) {
        int r = r0 + i * 8 + rr;
        float4 u = *(const float4*)&in[(size_t)r * DD + c0];
        s0 += u.x; q0 += u.x*u.x;  s1 += u.y; q1 += u.y*u.y;
        s2 += u.z; q2 += u.z*u.z;  s3 += u.w; q3 += u.w*u.w;
    }
    int lb = rr * 132 + chunk * 4;
    rs[lb+0]=s0; rs[lb+1]=s1; rs[lb+2]=s2; rs[lb+3]=s3;
    rq[lb+0]=q0; rq[lb+1]=q1; rq[lb+2]=q2; rq[lb+3]=q3;
    __syncthreads();
    float* part = ws + O_PART + (size_t)rg * 8192;
    if (t < 128) {                                    // finalize sums
        float a = 0.f;
        #pragma unroll
        for (int r2 = 0; r2 < 8; ++r2) a += rs[r2 * 132 + t];
        part[dbase + t] = a;
    } else {                                          // finalize sumsqs
        int ci = t - 128;
        float a = 0.f;
        #pragma unroll
        for (int r2 = 0; r2 < 8; ++r2) a += rq[r2 * 132 + ci];
        part[4096 + dbase + ci] = a;
    }
}

// ============ kB: inv-prologue + pure GEMM R = (in.inv) @ Wcat ==============
// 2048 blocks = 32 dgroups(128 d) x 64 rowgroups(64 rows). 8 blocks/CU.
// Thread: row = t&63, jq = readfirstlane(t>>6) -> j in [jq*8, jq*8+8).
__global__ __launch_bounds__(256, 8)
void kB(const float* __restrict__ in, const float* __restrict__ W,
        const float* __restrict__ Wstat, float* __restrict__ ws,
        float* __restrict__ ypart) {
    __shared__ __align__(16) float tile[64 * 33];     // 8.4 KB
    __shared__ __align__(16) float inv_s[128];
    int b = blockIdx.x, t = threadIdx.x;
    int dg = b & 31, rg = b >> 5;
    int dbase = dg * 128, rowbase = rg * 64;
    int chunk = t & 7, srow = t >> 3;                 // staging role (srow<32)
    int row = t & 63;
    int jq = __builtin_amdgcn_readfirstlane(t >> 6);  // wave-uniform -> s_load
    const float* inp = in + (size_t)(rowbase + srow) * DD + dbase + chunk * 4;
    float4 pf0 = *(const float4*)(inp);               // prefetch overlaps prologue
    float4 pf1 = *(const float4*)(inp + (size_t)32 * DD);
    {   // prologue: inv for this block's 128 cols from 16 KB L2-hot partials
        if (t < 128) {
            const float* part = ws + O_PART;
            float s = 0.f, q = 0.f;
            #pragma unroll
            for (int g = 0; g < 16; ++g) {
                s += part[(size_t)g * 8192 + dbase + t];
                q += part[(size_t)g * 8192 + 4096 + dbase + t];
            }
            float m = s * (1.0f / BB);
            float var = q * (1.0f / BB) - m * m; if (var < 0.f) var = 0.f;
            inv_s[t] = 1.0f / (sqrtf(var) + EPSF);
        }
        __syncthreads();
    }
    float acc[8];
    #pragma unroll
    for (int i = 0; i < 8; ++i) acc[i] = 0.f;
    // raw weight base: wave-uniform jq -> scalar loads (R7 lesson)
    const float* wbase = (jq < 2) ? (Wstat + jq * 8) : (W + (jq - 2) * 8);
    for (int stage = 0; stage < 4; ++stage) {
        int ds0 = stage * 32;
        float4 iv4 = *(const float4*)&inv_s[ds0 + chunk * 4];
        int b0 = srow * 33 + chunk * 4;               // scale folded into staging
        tile[b0 + 0] = pf0.x * iv4.x; tile[b0 + 1] = pf0.y * iv4.y;
        tile[b0 + 2] = pf0.z * iv4.z; tile[b0 + 3] = pf0.w * iv4.w;
        int b1 = (srow + 32) * 33 + chunk * 4;
        tile[b1 + 0] = pf1.x * iv4.x; tile[b1 + 1] = pf1.y * iv4.y;
        tile[b1 + 2] = pf1.z * iv4.z; tile[b1 + 3] = pf1.w * iv4.w;
        __syncthreads();
        if (stage < 3) {                              // prefetch next stage
            pf0 = *(const float4*)(inp + (stage + 1) * 32);
            pf1 = *(const float4*)(inp + (size_t)32 * DD + (stage + 1) * 32);
        }
        const float* trow = tile + row * 33;
        #pragma unroll 4
        for (int dl = 0; dl < 32; ++dl) {
            float xs = trow[dl];
            const float* wr = wbase + (size_t)(dbase + ds0 + dl) * 16;
            #pragma unroll
            for (int j = 0; j < 8; ++j) acc[j] += xs * wr[j];
        }
        __syncthreads();
    }
    float* dst = ypart + ((size_t)dg * BB + rowbase + row) * 32 + jq * 8;
    *(float4*)(dst + 0) = make_float4(acc[0], acc[1], acc[2], acc[3]);
    *(float4*)(dst + 4) = make_float4(acc[4], acc[5], acc[6], acc[7]);
}

// ====== kCE: per-block ypart reduce + gram atomics + spin + solve ===========
// 64 blocks x 512 threads, all co-resident (64 <= 256 CUs). Atomics-only
// cross-block communication; no global yz; no fences.
__global__ __launch_bounds__(512, 1)
void kCE(float* __restrict__ ws, float* __restrict__ out) {
    __shared__ __align__(16) float yzs[64 * 36];      // own 64 rows of [Ry|Rz|1]
    __shared__ float Sv[33], GA[17 * 17], gz[17 * 16], v[15][17], gad[15][16],
                     gzd[15][16], gu[17], u[17], st[2], wm[17 * 16];
    int b = blockIdx.x, t = threadIdx.x;
    int rowbase = b * 64;
    const float invB = 1.0f / BB;

    // phase 1: reduce 32 dgroup planes for own rows -> LDS (no global write)
    {
        int r = t >> 3, q = (t & 7) * 4;              // 512 threads = 64 rows x 8 quads
        const float* yp = ws + O_YPART;
        size_t off = (size_t)(rowbase + r) * 32 + q;
        float x0=0.f, x1=0.f, x2=0.f, x3=0.f;
        #pragma unroll 8
        for (int dg = 0; dg < 32; ++dg) {
            float4 vv = *(const float4*)&yp[(size_t)dg * (BB * 32) + off];
            x0 += vv.x; x1 += vv.y; x2 += vv.z; x3 += vv.w;
        }
        int lb = r * 36 + q;
        yzs[lb + 0] = x0; yzs[lb + 1] = x1; yzs[lb + 2] = x2; yzs[lb + 3] = x3;
        if (q == 0) yzs[r * 36 + 32] = 1.0f;          // ones column
    }
    __syncthreads();

    // phase 2: gram contribution for own 64 rows (8-way copies by b&7)
    float* gm8 = ws + O_GRAMM + (size_t)(b & 7) * 1120;
    for (int p = t; p < 561; p += 512) {              // upper-tri pairs i<=j<=32
        int i = 0, rem = p;
        while (rem >= 33 - i) { rem -= 33 - i; ++i; }
        int j = i + rem;
        float a2 = 0.f;
        #pragma unroll 8
        for (int r2 = 0; r2 < 64; ++r2)
            a2 += yzs[r2 * 36 + i] * yzs[r2 * 36 + j];
        atomicAdd(&gm8[i * 33 + j], a2);
    }

    // phase 3: arrival + spin. syncthreads drains vmcnt -> this block's gram
    // atomics are at the coherent point before the counter bump (release).
    __syncthreads();
    unsigned int* cnt = (unsigned int*)(ws + O_CNT);
    if (t == 0) {
        atomicAdd(cnt, 1u);
        while (__hip_atomic_load(cnt, __ATOMIC_RELAXED,
                                 __HIP_MEMORY_SCOPE_AGENT) < 64u)
            __builtin_amdgcn_s_sleep(8);
    }
    __syncthreads();

    // phase 4: solve, reading gram ONLY via coherent-point atomic loads
    const float* gm = ws + O_GRAMM;
    if (t < 33) {                                     // S_i = <R_i, 1> (i=32: B)
        float s = 0.f;
        #pragma unroll
        for (int m = 0; m < 8; ++m) s += agl(&gm[m * 1120 + gidx(t, 32)]);
        Sv[t] = s;
    }
    __syncthreads();
    for (int idx = t; idx < 17 * 17; idx += 512) {    // centered GA
        int p = idx / 17, q = idx % 17;
        float val;
        if (p < 16 && q < 16) {
            float raw = 0.f;
            #pragma unroll
            for (int m = 0; m < 8; ++m) raw += agl(&gm[m * 1120 + gidx(p, q)]);
            val = raw - Sv[p] * Sv[q] * invB;
        } else if (p == 16 && q == 16) val = (float)BB;
        else val = 0.f;                               // <P,1> = 0 exactly
        GA[idx] = val;
    }
    for (int idx = t; idx < 17 * 16; idx += 512) {    // centered gz
        int p = idx / 16, tt = idx % 16;
        float val = 0.f;
        if (p < 16) {
            float raw = 0.f;
            #pragma unroll
            for (int m = 0; m < 8; ++m) raw += agl(&gm[m * 1120 + gidx(p, 16 + tt)]);
            val = raw - Sv[p] * Sv[16 + tt] * invB;
        }
        gz[idx] = val;
    }
    if (t < 17) u[t] = (t == 0) ? 1.f : 0.f;
    __syncthreads();
    for (int i = 0; i < 15; ++i) {
        if (t < 17) {                                 // gu = GA @ u
            float s = 0.f;
            for (int q = 0; q < 17; ++q) s += GA[t * 17 + q] * u[q];
            gu[t] = s;
        }
        __syncthreads();
        if (t == 0) {                                 // stats of c_i
            float mean = gu[16] * invB, e2 = 0.f;
            for (int p = 0; p < 17; ++p) e2 += u[p] * gu[p];
            e2 *= invB;
            float var = e2 - mean * mean; if (var < 0.f) var = 0.f;
            st[0] = mean; st[1] = 1.0f / (sqrtf(var) + EPSF);
        }
        __syncthreads();
        if (t < 17) v[i][t] = (u[t] - (t == 16 ? st[0] : 0.f)) * st[1];
        __syncthreads();
        if (t < 16) {                                 // conv_i . Y[:,k]
            float s = 0.f;
            for (int p = 0; p < 17; ++p) s += v[i][p] * GA[p * 17 + t];
            gad[i][t] = s;
        } else if (t < 32) {                          // conv_i . Z[:,tt]
            int tt = t - 16;
            float s = 0.f;
            for (int p = 0; p < 17; ++p) s += v[i][p] * gz[p * 16 + tt];
            gzd[i][tt] = s;
        }
        __syncthreads();
        if (t < 17) {                                 // u_{i+1}
            float a2 = 0.f;
            for (int j = 0; j <= i; ++j) a2 += v[j][t] * gad[j][i + 1];
            u[t] = ((t == i + 1) ? 1.f : 0.f) - a2 * invB;
        }
        __syncthreads();
    }
    for (int idx = t; idx < 17 * 16; idx += 512) {
        int p = idx / 16, tt = idx % 16;
        float s = 0.f;
        for (int j = 0; j < tt; ++j) s += v[j][p] * gzd[j][tt];
        wm[idx] = s * invB;
    }
    __syncthreads();
    if (t < 16) {                                     // fold shifts into ones-row
        float adj = Sv[16 + t] * invB;
        for (int p = 0; p < 16; ++p) adj -= Sv[p] * invB * wm[p * 16 + t];
        wm[16 * 16 + t] += adj;
    }
    __syncthreads();
    if (t < 256) {                                    // epilogue: own 64 rows
        int row = t >> 2, c0 = (t & 3) * 4;
        const float* yr = yzs + row * 36;
        float o[4];
        #pragma unroll
        for (int k = 0; k < 4; ++k) o[k] = yr[16 + c0 + k] - wm[16 * 16 + c0 + k];
        #pragma unroll
        for (int p = 0; p < 16; ++p) {
            float yp = yr[p];
            #pragma unroll
            for (int k = 0; k < 4; ++k) o[k] -= yp * wm[p * 16 + c0 + k];
        }
        *(float4*)&out[(size_t)rowbase * 16 + t * 4] = make_float4(o[0], o[1], o[2], o[3]);
    }
}

extern "C" void kernel_launch(void* const* d_in, const int* in_sizes, int n_in,
                              void* d_out, int out_size, void* d_ws, size_t ws_size,
                              hipStream_t stream) {
    const float* in    = (const float*)d_in[0];
    const float* W     = (const float*)d_in[1];
    const float* Wstat = (const float*)d_in[2];
    float* ws  = (float*)d_ws;
    float* out = (float*)d_out;

    kA<<<dim3(512),  dim3(256), 0, stream>>>(in, ws);
    kB<<<dim3(2048), dim3(256), 0, stream>>>(in, W, Wstat, ws, ws + O_YPART);
    kCE<<<dim3(64),  dim3(512), 0, stream>>>(ws, out);
}